// Round 1
// 546.266 us; speedup vs baseline: 1.0061x; 1.0061x over previous
//
#include <hip/hip_runtime.h>
#include <hip/hip_bf16.h>
#include <stdint.h>

#define M_DIM 8192
#define N_DIM 4096
#define K_DIM 4096
#define BM 256
#define BN 256
#define BK 64
#define NT (K_DIM / BK)   // 64 K-tiles

#define CVT_BLOCKS 8192   // 33.5M elems / 16 per thread / 256
#define DQ_BLOCKS  8192   // 16.8M elems /  8 per thread / 256

typedef float f32x16 __attribute__((ext_vector_type(16)));
typedef __bf16 bf16x8 __attribute__((ext_vector_type(8)));
typedef short s16x8 __attribute__((ext_vector_type(8)));

// MFMA dispatch: prefer native __bf16 operand signature; fallback to short8.
template <typename AB>
__device__ __forceinline__ auto mfma_32x32x16(AB a, AB b, f32x16 c, int)
    -> decltype(__builtin_amdgcn_mfma_f32_32x32x16_bf16(a, b, c, 0, 0, 0)) {
  return __builtin_amdgcn_mfma_f32_32x32x16_bf16(a, b, c, 0, 0, 0);
}
template <typename AB>
__device__ __forceinline__ f32x16 mfma_32x32x16(AB a, AB b, f32x16 c, long) {
  return __builtin_amdgcn_mfma_f32_32x32x16_bf16(
      __builtin_bit_cast(s16x8, a), __builtin_bit_cast(s16x8, b), c, 0, 0, 0);
}

__device__ __forceinline__ uint16_t f2b(float f) {
  union { float f; uint32_t u; } v; v.f = f;
  uint32_t u = v.u;
  u += 0x7FFFu + ((u >> 16) & 1u);   // round-to-nearest-even
  return (uint16_t)(u >> 16);
}

// ---- fused pre-pass: blocks [0,CVT_BLOCKS) convert inp fp32->bf16 (16/thr);
//      blocks [CVT_BLOCKS, ..) dequant NF4 weight -> bf16 (8/thr, div-free) ----
__global__ __launch_bounds__(256) void prep(const float* __restrict__ inp,
                                            uint16_t* __restrict__ A_bf16,
                                            const float* __restrict__ w,
                                            const float* __restrict__ scales,
                                            const float* __restrict__ values,
                                            const float* __restrict__ pivots,
                                            uint16_t* __restrict__ B_bf16) {
  if (blockIdx.x < CVT_BLOCKS) {
    size_t t = (size_t)blockIdx.x * blockDim.x + threadIdx.x;
    const float4* p = (const float4*)inp + t * 4;
    uint4* q = (uint4*)A_bf16 + t * 2;
#pragma unroll
    for (int h = 0; h < 2; ++h) {
      float4 a = p[2 * h], b = p[2 * h + 1];
      uint4 o;
      o.x = (uint32_t)f2b(a.x) | ((uint32_t)f2b(a.y) << 16);
      o.y = (uint32_t)f2b(a.z) | ((uint32_t)f2b(a.w) << 16);
      o.z = (uint32_t)f2b(b.x) | ((uint32_t)f2b(b.y) << 16);
      o.w = (uint32_t)f2b(b.z) | ((uint32_t)f2b(b.w) << 16);
      q[h] = o;
    }
  } else {
    __shared__ float sv[16];
    if (threadIdx.x < 16) sv[threadIdx.x] = values[threadIdx.x];
    float pv[15];
#pragma unroll
    for (int j = 0; j < 15; ++j) pv[j] = pivots[j];   // uniform -> SGPRs
    __syncthreads();
    size_t t = (size_t)(blockIdx.x - CVT_BLOCKS) * blockDim.x + threadIdx.x;
    size_t base = t * 8;
    float scale = scales[base >> 6];
    // pv[j] < w/scale  <=>  pv[j]*scale < w  (scale > 0); clip redundant
    float psc[15];
#pragma unroll
    for (int j = 0; j < 15; ++j) psc[j] = pv[j] * scale;
    const float4* p = (const float4*)(w + base);
    float4 a = p[0], b = p[1];
    float e[8] = {a.x, a.y, a.z, a.w, b.x, b.y, b.z, b.w};
    uint32_t words[4];
#pragma unroll
    for (int i = 0; i < 4; ++i) {
      uint32_t hw[2];
#pragma unroll
      for (int h = 0; h < 2; ++h) {
        float x = e[2 * i + h];
        int idx = 0;
#pragma unroll
        for (int j = 0; j < 15; ++j) idx += (psc[j] < x) ? 1 : 0;  // searchsorted left
        hw[h] = f2b(sv[idx] * scale);   // 16-word table: broadcast, conflict-free
      }
      words[i] = hw[0] | (hw[1] << 16);
    }
    uint4 o = {words[0], words[1], words[2], words[3]};
    ((uint4*)B_bf16)[t] = o;
  }
}

// ============================================================================
// 256x256 8-wave deep-pipelined bf16 GEMM, C[m,n] = sum_k A[m,k]*B[n,k].
// 2 K-tile LDS buffers, each split into k-half sub-buffers (A0,B0,A1,B1).
// 4 phases/K-tile: phase = (kh, mh); each phase stages exactly one sub-buffer
// of tile t+1 and computes 8 x mfma_32x32x16. Counted vmcnt(4) twice per
// K-tile (never 0 in the loop). 16B-granule XOR swizzle (c ^= (r>>1)&3)
// applied on the pre-swizzled GLOBAL source (gload_lds dest stays linear) and
// on the ds_read address -> even 8-lanes-per-4-bank-group, conflict-free.
// ============================================================================

#define GLL(SRC, LOFF)                                                        \
  __builtin_amdgcn_global_load_lds(                                           \
      (__attribute__((address_space(1))) void*)(void*)(SRC),                  \
      (__attribute__((address_space(3))) void*)(smem + (LOFF)), 16, 0, 0)

#define STAGE_A(NB, KH, KEL)                                                  \
  do {                                                                        \
    GLL(Ab + gs0 + (KEL) + (KH) * 32, (NB) * 32768u + (KH) * 16384u + l0);    \
    GLL(Ab + gs1 + (KEL) + (KH) * 32, (NB) * 32768u + (KH) * 16384u + l1);    \
  } while (0)
#define STAGE_B(NB, KH, KEL)                                                  \
  do {                                                                        \
    GLL(Bb + gs0 + (KEL) + (KH) * 32,                                         \
        65536u + (NB) * 32768u + (KH) * 16384u + l0);                         \
    GLL(Bb + gs1 + (KEL) + (KH) * 32,                                         \
        65536u + (NB) * 32768u + (KH) * 16384u + l1);                         \
  } while (0)

// barrier sandwich: IR memory fence + raw s_barrier + machine sched fence
#define MIDBAR()                                                              \
  do {                                                                        \
    asm volatile("" ::: "memory");                                            \
    __builtin_amdgcn_s_barrier();                                             \
    __builtin_amdgcn_sched_barrier(0);                                        \
  } while (0)
#define VM4BAR()                                                              \
  do {                                                                        \
    asm volatile("s_waitcnt vmcnt(4)" ::: "memory");                          \
    __builtin_amdgcn_s_barrier();                                             \
    __builtin_amdgcn_sched_barrier(0);                                        \
  } while (0)

// phase mh=0: reads A rows [wm*128, +64) + ALL B frags (kept for phase mh=1)
#define PHASE0(CUR, NB, KH, KEL)                                              \
  do {                                                                        \
    const uint32_t _ab = (CUR) * 32768u + (KH) * 16384u + aoff;               \
    const uint32_t _bb = 65536u + (CUR) * 32768u + (KH) * 16384u + boff;      \
    bf16x8 a00 = *(const bf16x8*)(smem + _ab + cb0);                          \
    bf16x8 a10 = *(const bf16x8*)(smem + _ab + 2048u + cb0);                  \
    bf16x8 a01 = *(const bf16x8*)(smem + _ab + cb1);                          \
    bf16x8 a11 = *(const bf16x8*)(smem + _ab + 2048u + cb1);                  \
    b00 = *(const bf16x8*)(smem + _bb + cb0);                                 \
    b10 = *(const bf16x8*)(smem + _bb + 2048u + cb0);                         \
    b01 = *(const bf16x8*)(smem + _bb + cb1);                                 \
    b11 = *(const bf16x8*)(smem + _bb + 2048u + cb1);                         \
    STAGE_A(NB, KH, KEL);                                                     \
    MIDBAR();                                                                 \
    __builtin_amdgcn_s_setprio(1);                                            \
    acc[0][0] = mfma_32x32x16(a00, b00, acc[0][0], 0);                        \
    acc[0][1] = mfma_32x32x16(a00, b10, acc[0][1], 0);                        \
    acc[1][0] = mfma_32x32x16(a10, b00, acc[1][0], 0);                        \
    acc[1][1] = mfma_32x32x16(a10, b10, acc[1][1], 0);                        \
    acc[0][0] = mfma_32x32x16(a01, b01, acc[0][0], 0);                        \
    acc[0][1] = mfma_32x32x16(a01, b11, acc[0][1], 0);                        \
    acc[1][0] = mfma_32x32x16(a11, b01, acc[1][0], 0);                        \
    acc[1][1] = mfma_32x32x16(a11, b11, acc[1][1], 0);                        \
    __builtin_amdgcn_sched_barrier(0);                                        \
    __builtin_amdgcn_s_setprio(0);                                            \
    MIDBAR();                                                                 \
  } while (0)

// phase mh=1: reads A rows [wm*128+64, +64), reuses b-frags; trailing vmcnt(4)
#define PHASE1(CUR, NB, KH, KEL)                                              \
  do {                                                                        \
    const uint32_t _ab = (CUR) * 32768u + (KH) * 16384u + aoff + 4096u;       \
    bf16x8 a00 = *(const bf16x8*)(smem + _ab + cb0);                          \
    bf16x8 a10 = *(const bf16x8*)(smem + _ab + 2048u + cb0);                  \
    bf16x8 a01 = *(const bf16x8*)(smem + _ab + cb1);                          \
    bf16x8 a11 = *(const bf16x8*)(smem + _ab + 2048u + cb1);                  \
    STAGE_B(NB, KH, KEL);                                                     \
    MIDBAR();                                                                 \
    __builtin_amdgcn_s_setprio(1);                                            \
    acc[2][0] = mfma_32x32x16(a00, b00, acc[2][0], 0);                        \
    acc[2][1] = mfma_32x32x16(a00, b10, acc[2][1], 0);                        \
    acc[3][0] = mfma_32x32x16(a10, b00, acc[3][0], 0);                        \
    acc[3][1] = mfma_32x32x16(a10, b10, acc[3][1], 0);                        \
    acc[2][0] = mfma_32x32x16(a01, b01, acc[2][0], 0);                        \
    acc[2][1] = mfma_32x32x16(a01, b11, acc[2][1], 0);                        \
    acc[3][0] = mfma_32x32x16(a11, b01, acc[3][0], 0);                        \
    acc[3][1] = mfma_32x32x16(a11, b11, acc[3][1], 0);                        \
    __builtin_amdgcn_sched_barrier(0);                                        \
    __builtin_amdgcn_s_setprio(0);                                            \
    VM4BAR();                                                                 \
  } while (0)

__global__ __launch_bounds__(512, 2) void gemm_bt(const uint16_t* __restrict__ A,
                                                  const uint16_t* __restrict__ B,
                                                  float* __restrict__ C) {
  __shared__ char smem[131072];   // A: [buf][kh][256r][64B]; B at +65536
  const int tid = threadIdx.x;
  const int wave = tid >> 6;
  const int lane = tid & 63;

  // bijective XCD-aware swizzle: 512 blocks, 64 per XCD; consecutive wg share
  // the same A row-panel (hot in the XCD's L2 across the bn sweep)
  const int bid = blockIdx.x;
  const int wg = (bid & 7) * 64 + (bid >> 3);
  const int bm = wg >> 4;   // 0..31
  const int bn = wg & 15;   // 0..15

  const int wm = wave >> 2;   // 0..1 -> 128 rows of A
  const int wn = wave & 3;    // 0..3 ->  64 rows of B
  const int r31 = lane & 31;
  const int hi = lane >> 5;

  // ds_read lane constants: frag (ks) chunk = (2*ks + hi) ^ ((r31>>1)&3)
  const int swz = (r31 >> 1) & 3;
  const uint32_t cb0 = (uint32_t)(((hi ^ swz) * 16));
  const uint32_t cb1 = (uint32_t)((((2 + hi) ^ swz) * 16));
  const uint32_t aoff = (uint32_t)(wm * 8192 + r31 * 64);
  const uint32_t boff = (uint32_t)(wn * 4096 + r31 * 64);

  // staging: slot s covers LDS bytes [s*16, s*16+16) = (row=s>>2, c'=s&3);
  // data granule for that slot is global chunk c = c' ^ ((row>>1)&3)
  const int s0 = wave * 128 + lane;
  const int r0 = s0 >> 2;
  const uint32_t gs0 =
      (uint32_t)r0 * K_DIM + (uint32_t)((((s0 & 3) ^ ((r0 >> 1) & 3)) * 8));
  const int s1 = s0 + 64;
  const int r1 = s1 >> 2;
  const uint32_t gs1 =
      (uint32_t)r1 * K_DIM + (uint32_t)((((s1 & 3) ^ ((r1 >> 1) & 3)) * 8));
  const uint32_t l0 = (uint32_t)(wave * 2048);   // wave-uniform LDS dest bases
  const uint32_t l1 = l0 + 1024u;

  const uint16_t* Ab = A + (size_t)bm * BM * K_DIM;
  const uint16_t* Bb = B + (size_t)bn * BN * K_DIM;

  f32x16 acc[4][2] = {};

  // prologue: tile 0 -> buf0, order A0,B0,A1,B1; wait first k-half only
  STAGE_A(0u, 0u, 0u);
  STAGE_B(0u, 0u, 0u);
  STAGE_A(0u, 1u, 0u);
  STAGE_B(0u, 1u, 0u);
  asm volatile("s_waitcnt vmcnt(4)" ::: "memory");
  __builtin_amdgcn_s_barrier();
  __builtin_amdgcn_sched_barrier(0);

  // steady state invariant entering tile t: outstanding = A1,B1 of tile t (4).
  // ph(kh0,mh0): +A0' ; ph(kh0,mh1): +B0', vmcnt(4) -> A1,B1 landed.
  // ph(kh1,mh0): +A1' ; ph(kh1,mh1): +B1', vmcnt(4) -> A0',B0' landed.
  for (int kt2 = 0; kt2 < NT; kt2 += 2) {
    const uint32_t kel0 = (uint32_t)(kt2 + 1) * BK;
    const uint32_t kel1 =
        (uint32_t)((kt2 + 2 < NT) ? (kt2 + 2) : (NT - 1)) * BK;  // clamp: dead buf
    {
      bf16x8 b00, b10, b01, b11;
      PHASE0(0u, 1u, 0u, kel0);
      PHASE1(0u, 1u, 0u, kel0);
      PHASE0(0u, 1u, 1u, kel0);
      PHASE1(0u, 1u, 1u, kel0);
    }
    {
      bf16x8 b00, b10, b01, b11;
      PHASE0(1u, 0u, 0u, kel1);
      PHASE1(1u, 0u, 0u, kel1);
      PHASE0(1u, 0u, 1u, kel1);
      PHASE1(1u, 0u, 1u, kel1);
    }
  }

  // drain LDS-DMA before LDS dealloc / endpgm
  asm volatile("s_waitcnt vmcnt(0)" ::: "memory");

  // epilogue: C/D 32x32: col=lane&31, row=(reg&3)+8*(reg>>2)+4*(lane>>5)
  const int crow0 = bm * BM + wm * 128;
  const int ccol0 = bn * BN + wn * 64 + r31;
#pragma unroll
  for (int i = 0; i < 4; ++i)
#pragma unroll
    for (int j = 0; j < 2; ++j)
#pragma unroll
      for (int reg = 0; reg < 16; ++reg) {
        int row = i * 32 + (reg & 3) + 8 * (reg >> 2) + 4 * hi;
        C[(size_t)(crow0 + row) * N_DIM + ccol0 + j * 32] = acc[i][j][reg];
      }
}

extern "C" void kernel_launch(void* const* d_in, const int* in_sizes, int n_in,
                              void* d_out, int out_size, void* d_ws, size_t ws_size,
                              hipStream_t stream) {
  const float* inp    = (const float*)d_in[0];  // [4,2048,4096]
  const float* weight = (const float*)d_in[1];  // [4096,4096]
  const float* scales = (const float*)d_in[2];  // [262144,1]
  const float* values = (const float*)d_in[3];  // [16]
  const float* pivots = (const float*)d_in[4];  // [15]
  float* out = (float*)d_out;                   // [4,2048,4096] fp32

  uint16_t* A_bf16 = (uint16_t*)d_ws;                   // 8192*4096 bf16 = 64 MiB
  uint16_t* B_bf16 = A_bf16 + (size_t)M_DIM * K_DIM;    // 4096*4096 bf16 = 32 MiB

  prep<<<CVT_BLOCKS + DQ_BLOCKS, 256, 0, stream>>>(inp, A_bf16, weight, scales, values,
                                                   pivots, B_bf16);
  gemm_bt<<<dim3(512), 512, 0, stream>>>(A_bf16, B_bf16, out);
}

// Round 2
// 520.513 us; speedup vs baseline: 1.0559x; 1.0495x over previous
//
#include <hip/hip_runtime.h>
#include <hip/hip_bf16.h>
#include <stdint.h>

#define M_DIM 8192
#define N_DIM 4096
#define K_DIM 4096
#define BM 256
#define BN 256
#define BK 64
#define NT (K_DIM / BK)   // 64 K-tiles

#define CVT_BLOCKS 8192   // 33.5M floats / 4-per-thread / 256 / 4 iters
#define DQ_BLOCKS  8192   // 16.8M floats / 4-per-thread / 256 / 2 iters

typedef float f32x16 __attribute__((ext_vector_type(16)));
typedef __bf16 bf16x8 __attribute__((ext_vector_type(8)));
typedef short s16x8 __attribute__((ext_vector_type(8)));

// MFMA dispatch: prefer native __bf16 operand signature; fallback to short8.
template <typename AB>
__device__ __forceinline__ auto mfma_32x32x16(AB a, AB b, f32x16 c, int)
    -> decltype(__builtin_amdgcn_mfma_f32_32x32x16_bf16(a, b, c, 0, 0, 0)) {
  return __builtin_amdgcn_mfma_f32_32x32x16_bf16(a, b, c, 0, 0, 0);
}
template <typename AB>
__device__ __forceinline__ f32x16 mfma_32x32x16(AB a, AB b, f32x16 c, long) {
  return __builtin_amdgcn_mfma_f32_32x32x16_bf16(
      __builtin_bit_cast(s16x8, a), __builtin_bit_cast(s16x8, b), c, 0, 0, 0);
}

__device__ __forceinline__ uint16_t f2b(float f) {
  union { float f; uint32_t u; } v; v.f = f;
  uint32_t u = v.u;
  u += 0x7FFFu + ((u >> 16) & 1u);   // round-to-nearest-even
  return (uint16_t)(u >> 16);
}

// ---- fused pre-pass, fully lane-coalesced (16B/lane loads):
//      blocks [0,CVT_BLOCKS): inp fp32->bf16, 4 iters x float4/thread
//      blocks [CVT_BLOCKS,..): NF4 dequant -> bf16, 2 iters x float4/thread ----
__global__ __launch_bounds__(256) void prep(const float* __restrict__ inp,
                                            uint16_t* __restrict__ A_bf16,
                                            const float* __restrict__ w,
                                            const float* __restrict__ scales,
                                            const float* __restrict__ values,
                                            const float* __restrict__ pivots,
                                            uint16_t* __restrict__ B_bf16) {
  if (blockIdx.x < CVT_BLOCKS) {
    size_t t0 = (size_t)blockIdx.x * 256 + threadIdx.x;
    const float4* pin = (const float4*)inp;
    uint2* pout = (uint2*)A_bf16;
#pragma unroll
    for (int it = 0; it < 4; ++it) {
      size_t i = t0 + (size_t)it * ((size_t)CVT_BLOCKS * 256);
      float4 a = pin[i];
      uint2 o;
      o.x = (uint32_t)f2b(a.x) | ((uint32_t)f2b(a.y) << 16);
      o.y = (uint32_t)f2b(a.z) | ((uint32_t)f2b(a.w) << 16);
      pout[i] = o;
    }
  } else {
    __shared__ float sv[16];
    if (threadIdx.x < 16) sv[threadIdx.x] = values[threadIdx.x];
    float pv[15];
#pragma unroll
    for (int j = 0; j < 15; ++j) pv[j] = pivots[j];   // uniform -> SGPRs
    __syncthreads();
    size_t t0 = (size_t)(blockIdx.x - CVT_BLOCKS) * 256 + threadIdx.x;
    const float4* pw = (const float4*)w;
    uint2* pout = (uint2*)B_bf16;
#pragma unroll
    for (int it = 0; it < 2; ++it) {
      size_t i = t0 + (size_t)it * ((size_t)DQ_BLOCKS * 256);  // float4 index
      float scale = scales[i >> 4];   // 16 float4s per 64-elem group; 16-lane broadcast
      float psc[15];
#pragma unroll
      for (int j = 0; j < 15; ++j) psc[j] = pv[j] * scale;
      float4 a = pw[i];
      float e[4] = {a.x, a.y, a.z, a.w};
      uint32_t hw[4];
#pragma unroll
      for (int k = 0; k < 4; ++k) {
        int idx = 0;
#pragma unroll
        for (int j = 0; j < 15; ++j) idx += (psc[j] < e[k]) ? 1 : 0;  // searchsorted left
        hw[k] = f2b(sv[idx] * scale);
      }
      uint2 o = {hw[0] | (hw[1] << 16), hw[2] | (hw[3] << 16)};
      pout[i] = o;
    }
  }
}

// ============================================================================
// 256x256 8-wave bf16 GEMM, C[m,n] = sum_k A[m,k]*B[n,k]; 32x32x16 MFMA.
// TWO barriers per K-tile (mid + boundary), counted lgkmcnt pipeline:
// per kh-half: issue 12 ds_read_b128 (two 6-frag ksteps), lgkmcnt(6) ->
// 8 MFMA while second set drains, lgkmcnt(0) -> 8 MFMA. Staging leads by one
// K-tile with vmcnt(4) twice per tile (never 0 in loop). 16B-granule XOR
// swizzle (c ^= (r>>1)&3) applied on the pre-swizzled GLOBAL source
// (gload_lds dest stays linear) and on the ds_read address.
// ============================================================================

#define GLL(SRC, LOFF)                                                        \
  __builtin_amdgcn_global_load_lds(                                           \
      (__attribute__((address_space(1))) void*)(void*)(SRC),                  \
      (__attribute__((address_space(3))) void*)(smem + (LOFF)), 16, 0, 0)

#define STAGE_A(NB, KH, KEL)                                                  \
  do {                                                                        \
    GLL(Ab + gs0 + (KEL) + (KH) * 32, (NB) * 32768u + (KH) * 16384u + l0);    \
    GLL(Ab + gs1 + (KEL) + (KH) * 32, (NB) * 32768u + (KH) * 16384u + l1);    \
  } while (0)
#define STAGE_B(NB, KH, KEL)                                                  \
  do {                                                                        \
    GLL(Bb + gs0 + (KEL) + (KH) * 32,                                         \
        65536u + (NB) * 32768u + (KH) * 16384u + l0);                         \
    GLL(Bb + gs1 + (KEL) + (KH) * 32,                                         \
        65536u + (NB) * 32768u + (KH) * 16384u + l1);                         \
  } while (0)

// mid/boundary sync: counted vmcnt (4 newest loads may stay in flight) +
// raw barrier + machine sched fence
#define SYNC4()                                                               \
  do {                                                                        \
    asm volatile("s_waitcnt vmcnt(4)" ::: "memory");                          \
    __builtin_amdgcn_s_barrier();                                             \
    __builtin_amdgcn_sched_barrier(0);                                        \
  } while (0)

#define READ6(A0, A1, A2, A3, B0, B1, CUR, KH, CB)                            \
  do {                                                                        \
    const uint32_t _ab = (CUR) * 32768u + (KH) * 16384u + aoff;               \
    const uint32_t _bb = 65536u + (CUR) * 32768u + (KH) * 16384u + boff;      \
    A0 = *(const bf16x8*)(smem + _ab + (CB));                                 \
    A1 = *(const bf16x8*)(smem + _ab + 2048u + (CB));                         \
    A2 = *(const bf16x8*)(smem + _ab + 4096u + (CB));                         \
    A3 = *(const bf16x8*)(smem + _ab + 6144u + (CB));                         \
    B0 = *(const bf16x8*)(smem + _bb + (CB));                                 \
    B1 = *(const bf16x8*)(smem + _bb + 2048u + (CB));                         \
  } while (0)

#define MFMA8(A0, A1, A2, A3, B0, B1)                                         \
  do {                                                                        \
    acc[0][0] = mfma_32x32x16(A0, B0, acc[0][0], 0);                          \
    acc[0][1] = mfma_32x32x16(A0, B1, acc[0][1], 0);                          \
    acc[1][0] = mfma_32x32x16(A1, B0, acc[1][0], 0);                          \
    acc[1][1] = mfma_32x32x16(A1, B1, acc[1][1], 0);                          \
    acc[2][0] = mfma_32x32x16(A2, B0, acc[2][0], 0);                          \
    acc[2][1] = mfma_32x32x16(A2, B1, acc[2][1], 0);                          \
    acc[3][0] = mfma_32x32x16(A3, B0, acc[3][0], 0);                          \
    acc[3][1] = mfma_32x32x16(A3, B1, acc[3][1], 0);                          \
  } while (0)

// one kh-half: 12 reads issued up front, two 8-MFMA clusters with counted
// lgkm waits; stage issues split around the first cluster
#define HALF(CUR, NB, KH, KEL)                                                \
  do {                                                                        \
    bf16x8 xa0, xa1, xa2, xa3, xb0, xb1;                                      \
    bf16x8 ya0, ya1, ya2, ya3, yb0, yb1;                                      \
    READ6(xa0, xa1, xa2, xa3, xb0, xb1, CUR, KH, cb0);                        \
    READ6(ya0, ya1, ya2, ya3, yb0, yb1, CUR, KH, cb1);                        \
    STAGE_A(NB, KH, KEL);                                                     \
    asm volatile("s_waitcnt lgkmcnt(6)" ::: "memory");                        \
    __builtin_amdgcn_sched_barrier(0);                                        \
    __builtin_amdgcn_s_setprio(1);                                            \
    MFMA8(xa0, xa1, xa2, xa3, xb0, xb1);                                      \
    __builtin_amdgcn_s_setprio(0);                                            \
    STAGE_B(NB, KH, KEL);                                                     \
    asm volatile("s_waitcnt lgkmcnt(0)" ::: "memory");                        \
    __builtin_amdgcn_sched_barrier(0);                                        \
    __builtin_amdgcn_s_setprio(1);                                            \
    MFMA8(ya0, ya1, ya2, ya3, yb0, yb1);                                      \
    __builtin_amdgcn_s_setprio(0);                                            \
  } while (0)

// K-tile: 2 halves, 2 barriers. vmcnt invariant entering tile t:
// outstanding = {A1,B1 of t}. +A0',+B0' then vmcnt(4) -> {A1,B1} landed;
// +A1',+B1' then vmcnt(4) -> {A0',B0'} landed (next tile's first half).
#define TILE(CUR, NB, KEL)                                                    \
  do {                                                                        \
    HALF(CUR, NB, 0u, KEL);                                                   \
    SYNC4();                                                                  \
    HALF(CUR, NB, 1u, KEL);                                                   \
    SYNC4();                                                                  \
  } while (0)

__global__ __launch_bounds__(512, 2) void gemm_bt(const uint16_t* __restrict__ A,
                                                  const uint16_t* __restrict__ B,
                                                  float* __restrict__ C) {
  __shared__ char smem[131072];   // A: [buf][kh][256r][64B]; B at +65536
  const int tid = threadIdx.x;
  const int wave = tid >> 6;
  const int lane = tid & 63;

  // bijective XCD-aware swizzle: 512 blocks, 64 per XCD; consecutive wg share
  // the same A row-panel (hot in the XCD's L2 across the bn sweep)
  const int bid = blockIdx.x;
  const int wg = (bid & 7) * 64 + (bid >> 3);
  const int bm = wg >> 4;   // 0..31
  const int bn = wg & 15;   // 0..15

  const int wm = wave >> 2;   // 0..1 -> 128 rows of A
  const int wn = wave & 3;    // 0..3 ->  64 rows of B
  const int r31 = lane & 31;
  const int hi = lane >> 5;

  // ds_read lane constants: kstep q chunk = (2*q + hi) ^ ((r31>>1)&3)
  const int swz = (r31 >> 1) & 3;
  const uint32_t cb0 = (uint32_t)(((hi ^ swz) * 16));
  const uint32_t cb1 = (uint32_t)((((2 + hi) ^ swz) * 16));
  const uint32_t aoff = (uint32_t)(wm * 8192 + r31 * 64);
  const uint32_t boff = (uint32_t)(wn * 4096 + r31 * 64);

  // staging: slot s covers LDS bytes [s*16, s*16+16) = (row=s>>2, c'=s&3);
  // data granule for that slot is global chunk c = c' ^ ((row>>1)&3)
  const int s0 = wave * 128 + lane;
  const int r0 = s0 >> 2;
  const uint32_t gs0 =
      (uint32_t)r0 * K_DIM + (uint32_t)((((s0 & 3) ^ ((r0 >> 1) & 3)) * 8));
  const int s1 = s0 + 64;
  const int r1 = s1 >> 2;
  const uint32_t gs1 =
      (uint32_t)r1 * K_DIM + (uint32_t)((((s1 & 3) ^ ((r1 >> 1) & 3)) * 8));
  const uint32_t l0 = (uint32_t)(wave * 2048);   // wave-uniform LDS dest bases
  const uint32_t l1 = l0 + 1024u;

  const uint16_t* Ab = A + (size_t)bm * BM * K_DIM;
  const uint16_t* Bb = B + (size_t)bn * BN * K_DIM;

  f32x16 acc[4][2] = {};

  // prologue: tile 0 -> buf0, order A0,B0,A1,B1; wait first k-half only.
  // leaves outstanding = {A1,B1 of tile 0} = the loop invariant.
  STAGE_A(0u, 0u, 0u);
  STAGE_B(0u, 0u, 0u);
  STAGE_A(0u, 1u, 0u);
  STAGE_B(0u, 1u, 0u);
  asm volatile("s_waitcnt vmcnt(4)" ::: "memory");
  __builtin_amdgcn_s_barrier();
  __builtin_amdgcn_sched_barrier(0);

  for (int kt2 = 0; kt2 < NT; kt2 += 2) {
    const uint32_t kel0 = (uint32_t)(kt2 + 1) * BK;
    const uint32_t kel1 =
        (uint32_t)((kt2 + 2 < NT) ? (kt2 + 2) : (NT - 1)) * BK;  // clamp: dead buf
    TILE(0u, 1u, kel0);
    TILE(1u, 0u, kel1);
  }

  // drain LDS-DMA before LDS dealloc / endpgm
  asm volatile("s_waitcnt vmcnt(0)" ::: "memory");

  // epilogue: C/D 32x32: col=lane&31, row=(reg&3)+8*(reg>>2)+4*(lane>>5)
  const int crow0 = bm * BM + wm * 128;
  const int ccol0 = bn * BN + wn * 64 + r31;
#pragma unroll
  for (int i = 0; i < 4; ++i)
#pragma unroll
    for (int j = 0; j < 2; ++j)
#pragma unroll
      for (int reg = 0; reg < 16; ++reg) {
        int row = i * 32 + (reg & 3) + 8 * (reg >> 2) + 4 * hi;
        C[(size_t)(crow0 + row) * N_DIM + ccol0 + j * 32] = acc[i][j][reg];
      }
}

extern "C" void kernel_launch(void* const* d_in, const int* in_sizes, int n_in,
                              void* d_out, int out_size, void* d_ws, size_t ws_size,
                              hipStream_t stream) {
  const float* inp    = (const float*)d_in[0];  // [4,2048,4096]
  const float* weight = (const float*)d_in[1];  // [4096,4096]
  const float* scales = (const float*)d_in[2];  // [262144,1]
  const float* values = (const float*)d_in[3];  // [16]
  const float* pivots = (const float*)d_in[4];  // [15]
  float* out = (float*)d_out;                   // [4,2048,4096] fp32

  uint16_t* A_bf16 = (uint16_t*)d_ws;                   // 8192*4096 bf16 = 64 MiB
  uint16_t* B_bf16 = A_bf16 + (size_t)M_DIM * K_DIM;    // 4096*4096 bf16 = 32 MiB

  prep<<<CVT_BLOCKS + DQ_BLOCKS, 256, 0, stream>>>(inp, A_bf16, weight, scales, values,
                                                   pivots, B_bf16);
  gemm_bt<<<dim3(512), 512, 0, stream>>>(A_bf16, B_bf16, out);
}